// Round 7
// baseline (619.925 us; speedup 1.0000x reference)
//
#include <hip/hip_runtime.h>

#define S_ 256
#define N_ 384
#define C_ 512
#define H_ 8
#define R_ (N_*S_)
#define SPLITK 32
#define NPK (N_/SPLITK)   // 12

typedef _Float16 f16;
typedef _Float16 f16x8 __attribute__((ext_vector_type(8)));
typedef float f32x4 __attribute__((ext_vector_type(4)));

#define MFMA16(a,b,c) __builtin_amdgcn_mfma_f32_16x16x32_f16(a,b,c,0,0,0)

typedef __attribute__((address_space(3))) unsigned int as3_u32;
typedef __attribute__((address_space(1))) const unsigned int as1_u32;

// async global->LDS, 16B per lane; l must be the wave-uniform base
__device__ __forceinline__ void gl_lds16(const void* g, void* l) {
    __builtin_amdgcn_global_load_lds((as1_u32*)(unsigned long long)g,
                                     (as3_u32*)(unsigned long long)l, 16, 0, 0);
}

// [row][64] f16 tile; granule (8 f16 = 16B) XOR-swizzled with row&7
__device__ __forceinline__ int swz_off(int row, int g) {
    return row*64 + (((g) ^ (row & 7)) << 3);
}

// ---- 512-thread staging of a [128][64] f16 tile pair; linear LDS dest,
// inverse-swizzled global source (rule #21). 4 gl_lds per thread. ----
__device__ __forceinline__ void stage8(const f16* __restrict__ Ab,
                                       const f16* __restrict__ Bb,
                                       int stride, f16* As_, f16* Bs_,
                                       int tid, int wid) {
#pragma unroll
    for (int i = 0; i < 2; ++i) {
        int id = (i << 9) + tid;
        int row = id >> 3, g = (id & 7) ^ (row & 7);
        int lofs = ((i << 9) + (wid << 6)) << 4;   // wave-uniform LDS byte base
        gl_lds16(Ab + row * stride + (g << 3), (char*)As_ + lofs);
        gl_lds16(Bb + row * stride + (g << 3), (char*)Bs_ + lofs);
    }
}

// ---- K=64 MFMA step, 8-wave split: wave owns 64x32 (acc[4][2]) ----
__device__ __forceinline__ void mma8(const f16* As_, const f16* Bs_,
                                     int lane, int wr, int wc, f32x4 acc[4][2]) {
#pragma unroll
    for (int ks = 0; ks < 64; ks += 32) {
        int kg = (ks >> 3) + (lane >> 4);
        f16x8 af[4], bf[2];
#pragma unroll
        for (int m = 0; m < 4; ++m)
            af[m] = *(const f16x8*)&As_[swz_off(wr + (m << 4) + (lane & 15), kg)];
#pragma unroll
        for (int j = 0; j < 2; ++j)
            bf[j] = *(const f16x8*)&Bs_[swz_off(wc + (j << 4) + (lane & 15), kg)];
#pragma unroll
        for (int m = 0; m < 4; ++m)
#pragma unroll
            for (int j = 0; j < 2; ++j)
                acc[m][j] = MFMA16(af[m], bf[j], acc[m][j]);
    }
}

// fused weight-cast + msa transpose-cast
// msaT[r=(n*256+s)][c] = (f16)msa[s][n][c]
__global__ __launch_bounds__(256) void k_cast(const float* __restrict__ msa,
                                              const float* __restrict__ Wqkv,
                                              const float* __restrict__ Wout,
                                              f16* __restrict__ msaT,
                                              f16* __restrict__ Wq16,
                                              f16* __restrict__ Wo16) {
    int t = blockIdx.x * 256 + threadIdx.x;
    if (t < 1536 * C_) Wq16[t] = (f16)Wqkv[t];
    if (t < C_ * C_)   Wo16[t] = (f16)Wout[t];
    int r = t >> 6, cg = t & 63;
    int n = r >> 8, s = r & 255;
    const float* src = msa + (s * N_ + n) * C_ + (cg << 3);
    float4 lo = *(const float4*)src;
    float4 hi = *(const float4*)(src + 4);
    f16x8 v;
    v[0]=(f16)lo.x; v[1]=(f16)lo.y; v[2]=(f16)lo.z; v[3]=(f16)lo.w;
    v[4]=(f16)hi.x; v[5]=(f16)hi.y; v[6]=(f16)hi.z; v[7]=(f16)hi.w;
    *(f16x8*)(msaT + r * C_ + (cg << 3)) = v;
}

// qk[r][j](j<1024: q|k) and vB[n][h][tg][d][8] from msaT @ Wqkv^T + bqkv
// 8 waves, BK=64, double-buffered, proven sync discipline.
__global__ __launch_bounds__(512) void k_qkv(const f16* __restrict__ msaT,
                                             const f16* __restrict__ W,
                                             const float* __restrict__ bqkv,
                                             f16* __restrict__ qk,
                                             f16* __restrict__ vB) {
    int wg = (blockIdx.x & 7) * 1152 + (blockIdx.x >> 3);   // 9216 = 8*1152 exact
    int bx = wg / 12, by = wg % 12;
    int j0 = by << 7;
    int tid = threadIdx.x, lane = tid & 63, wid = tid >> 6;
    int wr = (wid >> 2) << 6, wc = (wid & 3) << 5;
    __shared__ f16 SH[32768];   // As0@0, Bs0@8192, As1@16384, Bs1@24576 (f16 units)
    const f16* Abase = msaT + (bx << 7) * C_;
    const f16* Bbase = W + j0 * C_;
    f32x4 acc[4][2] = {};
    stage8(Abase, Bbase, C_, SH, SH + 8192, tid, wid);
    __syncthreads();
    for (int kt = 0; kt < 8; ++kt) {
        int cur = kt & 1;
        if (kt < 7)
            stage8(Abase + ((kt + 1) << 6), Bbase + ((kt + 1) << 6), C_,
                   SH + ((cur ^ 1) << 14), SH + 8192 + ((cur ^ 1) << 14), tid, wid);
        mma8(SH + (cur << 14), SH + 8192 + (cur << 14), lane, wr, wc, acc);
        __syncthreads();
    }
    // ---- epilogue: [128][140] stage (conflict-free strides), coalesced stores ----
    if (by < 8) {
#pragma unroll
        for (int m = 0; m < 4; ++m) {
            int rl = wr + (m << 4) + ((lane >> 4) << 2);
#pragma unroll
            for (int j = 0; j < 2; ++j) {
                int col = wc + (j << 4) + (lane & 15);
                float bv = bqkv[j0 + col];
#pragma unroll
                for (int q = 0; q < 4; ++q)
                    SH[(rl + q) * 140 + col] = (f16)(acc[m][j][q] + bv);
            }
        }
        __syncthreads();
#pragma unroll
        for (int i = 0; i < 4; ++i) {
            int u = (i << 9) + tid;
            int row = u >> 4, seg = u & 15;
            *(f16x8*)(qk + ((bx << 7) + row) * 1024 + j0 + (seg << 3)) =
                *(const f16x8*)&SH[row * 140 + (seg << 3)];
        }
    } else {
        int n = bx >> 1, t0g = (bx & 1) << 7;
#pragma unroll
        for (int m = 0; m < 4; ++m) {
            int rl = wr + (m << 4) + ((lane >> 4) << 2);
#pragma unroll
            for (int j = 0; j < 2; ++j) {
                int col = wc + (j << 4) + (lane & 15);
                float bv = bqkv[1024 + ((by - 8) << 7) + col];
#pragma unroll
                for (int q = 0; q < 4; ++q)
                    SH[col * 140 + rl + q] = (f16)(acc[m][j][q] + bv);   // transpose
            }
        }
        __syncthreads();
        // blocked layout: vB[n][h][tg][d][e], 16B per store unit, consecutive
        // threads -> consecutive d -> fully coalesced 1KB lines
#pragma unroll
        for (int i = 0; i < 4; ++i) {
            int u = (i << 9) + tid;          // 0..2047
            int c6 = u & 63, hh = (u >> 6) & 1, sg = u >> 7;   // sg 0..15
            int lcol = (hh << 6) + c6;
            int jg = ((by - 8) << 7) + lcol;
            int h = jg >> 6;
            *(f16x8*)(vB + (((n * H_ + h) << 5) + (t0g >> 3) + sg) * 512 + (c6 << 3)) =
                *(const f16x8*)&SH[lcol * 140 + (sg << 3)];
        }
    }
}

// partial logits: logP[sk][h][s][t] = sum_{n in chunk, d} q[n,s,h,d]*k[n,t,h,d]
__global__ __launch_bounds__(512) void k_logits(const f16* __restrict__ qk,
                                                float* __restrict__ logP) {
    int wg = (blockIdx.x & 7) * 128 + (blockIdx.x >> 3);    // 1024 = 8*128 exact
    int sk = wg >> 5, rem = wg & 31, h = rem >> 2, sb = (rem >> 1) & 1, tb = rem & 1;
    int s0 = sb << 7, t0 = tb << 7, n0 = sk * NPK;
    int tid = threadIdx.x, lane = tid & 63, wid = tid >> 6;
    int wr = (wid >> 2) << 6, wc = (wid & 3) << 5;
    __shared__ f16 SH[32768];
    const f16* Aroot = qk + s0 * 1024 + (h << 6);
    const f16* Broot = qk + t0 * 1024 + 512 + (h << 6);
    f32x4 acc[4][2] = {};
    stage8(Aroot + n0 * S_ * 1024, Broot + n0 * S_ * 1024, 1024,
           SH, SH + 8192, tid, wid);
    __syncthreads();
    for (int t = 0; t < NPK; ++t) {
        int cur = t & 1;
        if (t < NPK - 1) {
            int n = n0 + t + 1;
            stage8(Aroot + n * S_ * 1024, Broot + n * S_ * 1024, 1024,
                   SH + ((cur ^ 1) << 14), SH + 8192 + ((cur ^ 1) << 14), tid, wid);
        }
        mma8(SH + (cur << 14), SH + 8192 + (cur << 14), lane, wr, wc, acc);
        __syncthreads();
    }
#pragma unroll
    for (int m = 0; m < 4; ++m) {
        int rl = wr + (m << 4) + ((lane >> 4) << 2);
#pragma unroll
        for (int j = 0; j < 2; ++j) {
            int tc = t0 + wc + (j << 4) + (lane & 15);
#pragma unroll
            for (int q = 0; q < 4; ++q)
                logP[((sk * H_ + h) * S_ + s0 + rl + q) * S_ + tc] = acc[m][j][q];
        }
    }
}

__global__ __launch_bounds__(256) void k_softmax(const float* __restrict__ logP,
                                                 const int* __restrict__ mask,
                                                 f16* __restrict__ attn) {
    int hs = blockIdx.x;  // h*256 + s
    int t = threadIdx.x, lane = t & 63, wid = t >> 6;
    float v = 0.f;
#pragma unroll
    for (int sk = 0; sk < SPLITK; ++sk)
        v += logP[(sk * H_ * S_ + hs) * S_ + t];
    v *= 0.125f;
    if (mask[t] == 0) v = -1e9f;
    __shared__ float redm[4], reds[4];
    float m_ = v;
    for (int o = 32; o > 0; o >>= 1) m_ = fmaxf(m_, __shfl_xor(m_, o));
    if (lane == 0) redm[wid] = m_;
    __syncthreads();
    float bm = fmaxf(fmaxf(redm[0], redm[1]), fmaxf(redm[2], redm[3]));
    float e = __expf(v - bm);
    float s_ = e;
    for (int o = 32; o > 0; o >>= 1) s_ += __shfl_xor(s_, o);
    if (lane == 0) reds[wid] = s_;
    __syncthreads();
    float tot = reds[0] + reds[1] + reds[2] + reds[3];
    attn[hs * S_ + t] = (f16)(e / tot);
}

// attn_out[n][s][h*64+d] = sum_t attn[h][s][t] * vB[n][h][t][d]
// A staged via gl_lds (attn is L2-hot); B-frags read DIRECTLY from global
// vB blocked layout (coalesced). LDS 36 KB -> 4 blocks/CU.
__global__ __launch_bounds__(256) void k_pv(const f16* __restrict__ attn,
                                            const f16* __restrict__ vB,
                                            f16* __restrict__ attn_out) {
    int n = blockIdx.x >> 3, h = blockIdx.x & 7;
    int tid = threadIdx.x, lane = tid & 63, wid = tid >> 6;
    __shared__ f16 SH[17920];                    // As 256x64 (16384) / epi [128][140]
    f16* As_ = SH;
    f32x4 acc[4][4] = {};
    const f16* Ab = attn + h * S_ * S_;
    const f16* vBb = vB + ((n * H_ + h) << 5) * 512;   // [tg][d][8]
    for (int tt = 0; tt < 4; ++tt) {
        int t0 = tt << 6;
        __syncthreads();
#pragma unroll
        for (int i = 0; i < 8; ++i) {           // As: 256 rows x 64
            int id = (i << 8) + tid;
            int row = id >> 3, g = (id & 7) ^ (row & 7);
            int lofs = ((i << 8) + (wid << 6)) << 4;
            gl_lds16(Ab + row * S_ + t0 + (g << 3), (char*)As_ + lofs);
        }
        __syncthreads();
#pragma unroll
        for (int ks = 0; ks < 64; ks += 32) {
            int kg = (ks >> 3) + (lane >> 4);
            f16x8 af[4], bf[4];
#pragma unroll
            for (int m = 0; m < 4; ++m)
                af[m] = *(const f16x8*)&As_[swz_off((wid << 6) + (m << 4) + (lane & 15), kg)];
#pragma unroll
            for (int j = 0; j < 4; ++j)
                bf[j] = *(const f16x8*)(vBb + ((t0 >> 3) + kg) * 512 +
                                        (((j << 4) + (lane & 15)) << 3));
#pragma unroll
            for (int m = 0; m < 4; ++m)
#pragma unroll
                for (int j = 0; j < 4; ++j)
                    acc[m][j] = MFMA16(af[m], bf[j], acc[m][j]);
        }
    }
    // epilogue: [128][140] stage halves, coalesced f16x8 stores
#pragma unroll
    for (int p = 0; p < 2; ++p) {
        __syncthreads();
#pragma unroll
        for (int mm = 0; mm < 2; ++mm) {
            int m = 2 * p + mm;
            int rl = ((m & 1) << 4) + ((lane >> 4) << 2);
            int lrow = (wid << 5) + rl;                      // 0..127
#pragma unroll
            for (int j = 0; j < 4; ++j) {
                int d = (j << 4) + (lane & 15);
#pragma unroll
                for (int q = 0; q < 4; ++q)
                    SH[(lrow + q) * 140 + d] = (f16)acc[m][j][q];
            }
        }
        __syncthreads();
#pragma unroll
        for (int i = 0; i < 4; ++i) {
            int u = tid + (i << 8);
            int row = u >> 3, seg = u & 7;
            int s = ((row >> 5) << 6) + (p << 5) + (row & 31);
            *(f16x8*)(attn_out + (n * S_ + s) * C_ + (h << 6) + (seg << 3)) =
                *(const f16x8*)&SH[row * 140 + (seg << 3)];
        }
    }
}

// y = attn_out @ Wout^T + bout; x = msaT + y; LayerNorm(x) -> out[s][n][c]
// A staged via gl_lds; Wo fragments streamed from global (L2-resident, 512 KB).
__global__ __launch_bounds__(512) void k_out_ln(const f16* __restrict__ attn_out,
                                                const f16* __restrict__ Wo,
                                                const float* __restrict__ bout,
                                                const f16* __restrict__ msaT,
                                                const float* __restrict__ gamma,
                                                const float* __restrict__ beta,
                                                float* __restrict__ out) {
    int r0 = blockIdx.x << 6;
    int n = r0 >> 8, s0 = r0 & 255;
    int tid = threadIdx.x, lane = tid & 63, wid = tid >> 6;
    __shared__ f16 As_[4096];                    // 64x64 tile
    __shared__ float redS[8][64], redQ[8][64], muS[64], rsS[64];
    f32x4 acc[4][4] = {};
    const f16* Wob = Wo + ((wid << 6) + (lane & 15)) * C_;
    for (int kt = 0; kt < 8; ++kt) {
        int c0 = kt << 6;
        __syncthreads();
        {                                         // As: 64 rows x 64 (1 instr/thread)
            int row = tid >> 3, g = (tid & 7) ^ (row & 7);
            int lofs = (wid << 6) << 4;
            gl_lds16(attn_out + (r0 + row) * C_ + c0 + (g << 3), (char*)As_ + lofs);
        }
        __syncthreads();
#pragma unroll
        for (int ks = 0; ks < 64; ks += 32) {
            int kg = (ks >> 3) + (lane >> 4);
            f16x8 af[4], bf[4];
#pragma unroll
            for (int m = 0; m < 4; ++m)
                af[m] = *(const f16x8*)&As_[swz_off((m << 4) + (lane & 15), kg)];
#pragma unroll
            for (int j = 0; j < 4; ++j)
                bf[j] = *(const f16x8*)(Wob + (j << 4) * C_ + c0 + (kg << 3));
#pragma unroll
            for (int m = 0; m < 4; ++m)
#pragma unroll
                for (int j = 0; j < 4; ++j)
                    acc[m][j] = MFMA16(af[m], bf[j], acc[m][j]);
        }
    }
    float psum[4][4] = {}, psq[4][4] = {};
#pragma unroll
    for (int m = 0; m < 4; ++m)
#pragma unroll
        for (int j = 0; j < 4; ++j) {
            int c = (wid << 6) + (j << 4) + (lane & 15);
            float bj = bout[c];
#pragma unroll
            for (int q = 0; q < 4; ++q) {
                int rl = (m << 4) + ((lane >> 4) << 2) + q;
                float x = acc[m][j][q] + bj + (float)msaT[(r0 + rl) * C_ + c];
                acc[m][j][q] = x;
                psum[m][q] += x;
                psq[m][q] += x * x;
            }
        }
#pragma unroll
    for (int m = 0; m < 4; ++m)
#pragma unroll
        for (int q = 0; q < 4; ++q)
            for (int o = 1; o < 16; o <<= 1) {
                psum[m][q] += __shfl_xor(psum[m][q], o);
                psq[m][q]  += __shfl_xor(psq[m][q], o);
            }
    if ((lane & 15) == 0) {
#pragma unroll
        for (int m = 0; m < 4; ++m)
#pragma unroll
            for (int q = 0; q < 4; ++q) {
                int rl = (m << 4) + ((lane >> 4) << 2) + q;
                redS[wid][rl] = psum[m][q];
                redQ[wid][rl] = psq[m][q];
            }
    }
    __syncthreads();
    if (tid < 64) {
        float t1 = 0.f, t2 = 0.f;
#pragma unroll
        for (int w = 0; w < 8; ++w) { t1 += redS[w][tid]; t2 += redQ[w][tid]; }
        float mu = t1 * (1.0f / 512.0f);
        float var = t2 * (1.0f / 512.0f) - mu * mu;
        muS[tid] = mu;
        rsS[tid] = rsqrtf(var + 1e-5f);
    }
    __syncthreads();
#pragma unroll
    for (int m = 0; m < 4; ++m)
#pragma unroll
        for (int j = 0; j < 4; ++j) {
            int c = (wid << 6) + (j << 4) + (lane & 15);
            float g = gamma[c], bb = beta[c];
#pragma unroll
            for (int q = 0; q < 4; ++q) {
                int rl = (m << 4) + ((lane >> 4) << 2) + q;
                int s = s0 + rl;
                float y = (acc[m][j][q] - muS[rl]) * rsS[rl] * g + bb;
                out[(s * N_ + n) * C_ + c] = y;
            }
        }
}

extern "C" void kernel_launch(void* const* d_in, const int* in_sizes, int n_in,
                              void* d_out, int out_size, void* d_ws, size_t ws_size,
                              hipStream_t stream) {
    const float* msa   = (const float*)d_in[0];
    const int*   mask  = (const int*)d_in[1];
    const float* Wqkv  = (const float*)d_in[2];
    const float* bqkv  = (const float*)d_in[3];
    const float* Wout  = (const float*)d_in[4];
    const float* bout  = (const float*)d_in[5];
    const float* gamma = (const float*)d_in[6];
    const float* beta  = (const float*)d_in[7];
    float* out = (float*)d_out;
    char* ws = (char*)d_ws;

    f16*   qk   = (f16*)(ws);                        // 201,326,592 B
    f16*   vB   = (f16*)(ws + 201326592);            // 100,663,296 B
    f16*   msaT = (f16*)(ws + 301989888);            // 100,663,296 B
    f16*   attn = (f16*)(ws + 402653184);            //   1,048,576 B
    f16*   Wq16 = (f16*)(ws + 403701760);            //   1,572,864 B
    f16*   Wo16 = (f16*)(ws + 405274624);            //     524,288 B
    float* logP = out;                               // d_out as scratch (67 MB of 201 MB);
                                                     // k_out_ln overwrites d_out last
    f16*   attn_out = qk;                            // alias: q/k dead after k_logits

    k_cast<<<dim3(24576), dim3(256), 0, stream>>>(msa, Wqkv, Wout, msaT, Wq16, Wo16);
    k_qkv<<<dim3(9216), dim3(512), 0, stream>>>(msaT, Wq16, bqkv, qk, vB);
    k_logits<<<dim3(1024), dim3(512), 0, stream>>>(qk, logP);
    k_softmax<<<dim3(2048), dim3(256), 0, stream>>>(logP, mask, attn);
    k_pv<<<dim3(3072), dim3(256), 0, stream>>>(attn, vB, attn_out);
    k_out_ln<<<dim3(1536), dim3(512), 0, stream>>>(attn_out, Wo16, bout, msaT, gamma, beta, out);
}

// Round 8
// 563.263 us; speedup vs baseline: 1.1006x; 1.1006x over previous
//
#include <hip/hip_runtime.h>

#define S_ 256
#define N_ 384
#define C_ 512
#define H_ 8
#define R_ (N_*S_)
#define SPLITK 32
#define NPK (N_/SPLITK)   // 12

typedef _Float16 f16;
typedef _Float16 f16x8 __attribute__((ext_vector_type(8)));
typedef float f32x4 __attribute__((ext_vector_type(4)));

#define MFMA16(a,b,c) __builtin_amdgcn_mfma_f32_16x16x32_f16(a,b,c,0,0,0)

typedef __attribute__((address_space(3))) unsigned int as3_u32;
typedef __attribute__((address_space(1))) const unsigned int as1_u32;

// async global->LDS, 16B per lane; l must be the wave-uniform base
__device__ __forceinline__ void gl_lds16(const void* g, void* l) {
    __builtin_amdgcn_global_load_lds((as1_u32*)(unsigned long long)g,
                                     (as3_u32*)(unsigned long long)l, 16, 0, 0);
}

// [row][64] f16 tile; granule (8 f16 = 16B) XOR-swizzled with row&7
__device__ __forceinline__ int swz_off(int row, int g) {
    return row*64 + (((g) ^ (row & 7)) << 3);
}

// ---- 512-thread staging of a [128][64] f16 tile pair; linear LDS dest,
// inverse-swizzled global source (rule #21). 4 gl_lds per thread. ----
__device__ __forceinline__ void stage8(const f16* __restrict__ Ab,
                                       const f16* __restrict__ Bb,
                                       int stride, f16* As_, f16* Bs_,
                                       int tid, int wid) {
#pragma unroll
    for (int i = 0; i < 2; ++i) {
        int id = (i << 9) + tid;
        int row = id >> 3, g = (id & 7) ^ (row & 7);
        int lofs = ((i << 9) + (wid << 6)) << 4;   // wave-uniform LDS byte base
        gl_lds16(Ab + row * stride + (g << 3), (char*)As_ + lofs);
        gl_lds16(Bb + row * stride + (g << 3), (char*)Bs_ + lofs);
    }
}

// ---- K=64 MFMA step, 8-wave split: wave owns 64x32 (acc[4][2]) ----
__device__ __forceinline__ void mma8(const f16* As_, const f16* Bs_,
                                     int lane, int wr, int wc, f32x4 acc[4][2]) {
#pragma unroll
    for (int ks = 0; ks < 64; ks += 32) {
        int kg = (ks >> 3) + (lane >> 4);
        f16x8 af[4], bf[2];
#pragma unroll
        for (int m = 0; m < 4; ++m)
            af[m] = *(const f16x8*)&As_[swz_off(wr + (m << 4) + (lane & 15), kg)];
#pragma unroll
        for (int j = 0; j < 2; ++j)
            bf[j] = *(const f16x8*)&Bs_[swz_off(wc + (j << 4) + (lane & 15), kg)];
#pragma unroll
        for (int m = 0; m < 4; ++m)
#pragma unroll
            for (int j = 0; j < 2; ++j)
                acc[m][j] = MFMA16(af[m], bf[j], acc[m][j]);
    }
}

// ---- K=64 MFMA step, 4-wave split (k_pv, k_out_ln): acc[4][4] ----
__device__ __forceinline__ void frag_mma64(const f16* As_, const f16* Bs_,
                                           int lane, int wr, int wc, f32x4 acc[4][4]) {
#pragma unroll
    for (int ks = 0; ks < 64; ks += 32) {
        int kg = (ks >> 3) + (lane >> 4);
        f16x8 af[4], bf[4];
#pragma unroll
        for (int m = 0; m < 4; ++m)
            af[m] = *(const f16x8*)&As_[swz_off(wr + (m << 4) + (lane & 15), kg)];
#pragma unroll
        for (int j = 0; j < 4; ++j)
            bf[j] = *(const f16x8*)&Bs_[swz_off(wc + (j << 4) + (lane & 15), kg)];
#pragma unroll
        for (int m = 0; m < 4; ++m)
#pragma unroll
            for (int j = 0; j < 4; ++j)
                acc[m][j] = MFMA16(af[m], bf[j], acc[m][j]);
    }
}

// fused weight-cast + msa transpose-cast
// msaT[r=(n*256+s)][c] = (f16)msa[s][n][c]
__global__ __launch_bounds__(256) void k_cast(const float* __restrict__ msa,
                                              const float* __restrict__ Wqkv,
                                              const float* __restrict__ Wout,
                                              f16* __restrict__ msaT,
                                              f16* __restrict__ Wq16,
                                              f16* __restrict__ Wo16) {
    int t = blockIdx.x * 256 + threadIdx.x;
    if (t < 1536 * C_) Wq16[t] = (f16)Wqkv[t];
    if (t < C_ * C_)   Wo16[t] = (f16)Wout[t];
    int r = t >> 6, cg = t & 63;
    int n = r >> 8, s = r & 255;
    const float* src = msa + (s * N_ + n) * C_ + (cg << 3);
    float4 lo = *(const float4*)src;
    float4 hi = *(const float4*)(src + 4);
    f16x8 v;
    v[0]=(f16)lo.x; v[1]=(f16)lo.y; v[2]=(f16)lo.z; v[3]=(f16)lo.w;
    v[4]=(f16)hi.x; v[5]=(f16)hi.y; v[6]=(f16)hi.z; v[7]=(f16)hi.w;
    *(f16x8*)(msaT + r * C_ + (cg << 3)) = v;
}

// qk[r][j](j<1024: q|k) and vT[n][h][d][t] from msaT @ Wqkv^T + bqkv
// 8 waves, BK=64, double-buffered, counted-vmcnt pipeline with
// asm "memory" barriers (compiler-fenced; see R8 theory for the audit).
__global__ __launch_bounds__(512) void k_qkv(const f16* __restrict__ msaT,
                                             const f16* __restrict__ W,
                                             const float* __restrict__ bqkv,
                                             f16* __restrict__ qk,
                                             f16* __restrict__ vT) {
    int wg = (blockIdx.x & 7) * 1152 + (blockIdx.x >> 3);   // 9216 = 8*1152 exact
    int bx = wg / 12, by = wg % 12;
    int j0 = by << 7;
    int tid = threadIdx.x, lane = tid & 63, wid = tid >> 6;
    int wr = (wid >> 2) << 6, wc = (wid & 3) << 5;
    __shared__ f16 SH[32768];   // As0@0, Bs0@8192, As1@16384, Bs1@24576 (f16 units)
    const f16* Abase = msaT + (bx << 7) * C_;
    const f16* Bbase = W + j0 * C_;
    f32x4 acc[4][2] = {};
    stage8(Abase, Bbase, C_, SH, SH + 8192, tid, wid);
    for (int kt = 0; kt < 8; ++kt) {
        int cur = kt & 1;
        if (kt < 7) {
            stage8(Abase + ((kt + 1) << 6), Bbase + ((kt + 1) << 6), C_,
                   SH + ((cur ^ 1) << 14), SH + 8192 + ((cur ^ 1) << 14), tid, wid);
            asm volatile("s_waitcnt vmcnt(4)" ::: "memory");
        } else {
            asm volatile("s_waitcnt vmcnt(0)" ::: "memory");
        }
        asm volatile("s_barrier" ::: "memory");
        mma8(SH + (cur << 14), SH + 8192 + (cur << 14), lane, wr, wc, acc);
        asm volatile("s_barrier" ::: "memory");
    }
    // ---- epilogue: [128][140] stage (conflict-free strides), coalesced stores ----
    if (by < 8) {
#pragma unroll
        for (int m = 0; m < 4; ++m) {
            int rl = wr + (m << 4) + ((lane >> 4) << 2);
#pragma unroll
            for (int j = 0; j < 2; ++j) {
                int col = wc + (j << 4) + (lane & 15);
                float bv = bqkv[j0 + col];
#pragma unroll
                for (int q = 0; q < 4; ++q)
                    SH[(rl + q) * 140 + col] = (f16)(acc[m][j][q] + bv);
            }
        }
        __syncthreads();
#pragma unroll
        for (int i = 0; i < 4; ++i) {
            int u = (i << 9) + tid;
            int row = u >> 4, seg = u & 15;
            *(f16x8*)(qk + ((bx << 7) + row) * 1024 + j0 + (seg << 3)) =
                *(const f16x8*)&SH[row * 140 + (seg << 3)];
        }
    } else {
        int n = bx >> 1, t0g = (bx & 1) << 7;
#pragma unroll
        for (int m = 0; m < 4; ++m) {
            int rl = wr + (m << 4) + ((lane >> 4) << 2);
#pragma unroll
            for (int j = 0; j < 2; ++j) {
                int col = wc + (j << 4) + (lane & 15);
                float bv = bqkv[1024 + ((by - 8) << 7) + col];
#pragma unroll
                for (int q = 0; q < 4; ++q)
                    SH[col * 140 + rl + q] = (f16)(acc[m][j][q] + bv);   // transpose
            }
        }
        __syncthreads();
#pragma unroll
        for (int i = 0; i < 4; ++i) {
            int u = (i << 9) + tid;
            int lcol = u >> 4, seg = u & 15;
            int jg = ((by - 8) << 7) + lcol;
            *(f16x8*)(vT + ((n * H_ + (jg >> 6)) * 64 + (jg & 63)) * S_ + t0g + (seg << 3)) =
                *(const f16x8*)&SH[lcol * 140 + (seg << 3)];
        }
    }
}

// partial logits: logP[sk][h][s][t] = sum_{n in chunk, d} q[n,s,h,d]*k[n,t,h,d]
// 8 waves, K=64 per n-iteration, counted-vmcnt pipeline (same template).
__global__ __launch_bounds__(512) void k_logits(const f16* __restrict__ qk,
                                                float* __restrict__ logP) {
    int wg = (blockIdx.x & 7) * 128 + (blockIdx.x >> 3);    // 1024 = 8*128 exact
    int sk = wg >> 5, rem = wg & 31, h = rem >> 2, sb = (rem >> 1) & 1, tb = rem & 1;
    int s0 = sb << 7, t0 = tb << 7, n0 = sk * NPK;
    int tid = threadIdx.x, lane = tid & 63, wid = tid >> 6;
    int wr = (wid >> 2) << 6, wc = (wid & 3) << 5;
    __shared__ f16 SH[32768];
    const f16* Aroot = qk + s0 * 1024 + (h << 6);
    const f16* Broot = qk + t0 * 1024 + 512 + (h << 6);
    f32x4 acc[4][2] = {};
    stage8(Aroot + n0 * S_ * 1024, Broot + n0 * S_ * 1024, 1024,
           SH, SH + 8192, tid, wid);
    for (int t = 0; t < NPK; ++t) {
        int cur = t & 1;
        if (t < NPK - 1) {
            int n = n0 + t + 1;
            stage8(Aroot + n * S_ * 1024, Broot + n * S_ * 1024, 1024,
                   SH + ((cur ^ 1) << 14), SH + 8192 + ((cur ^ 1) << 14), tid, wid);
            asm volatile("s_waitcnt vmcnt(4)" ::: "memory");
        } else {
            asm volatile("s_waitcnt vmcnt(0)" ::: "memory");
        }
        asm volatile("s_barrier" ::: "memory");
        mma8(SH + (cur << 14), SH + 8192 + (cur << 14), lane, wr, wc, acc);
        asm volatile("s_barrier" ::: "memory");
    }
#pragma unroll
    for (int m = 0; m < 4; ++m) {
        int rl = wr + (m << 4) + ((lane >> 4) << 2);
#pragma unroll
        for (int j = 0; j < 2; ++j) {
            int tc = t0 + wc + (j << 4) + (lane & 15);
#pragma unroll
            for (int q = 0; q < 4; ++q)
                logP[((sk * H_ + h) * S_ + s0 + rl + q) * S_ + tc] = acc[m][j][q];
        }
    }
}

__global__ __launch_bounds__(256) void k_softmax(const float* __restrict__ logP,
                                                 const int* __restrict__ mask,
                                                 f16* __restrict__ attn) {
    int hs = blockIdx.x;  // h*256 + s
    int t = threadIdx.x, lane = t & 63, wid = t >> 6;
    float v = 0.f;
#pragma unroll
    for (int sk = 0; sk < SPLITK; ++sk)
        v += logP[(sk * H_ * S_ + hs) * S_ + t];
    v *= 0.125f;
    if (mask[t] == 0) v = -1e9f;
    __shared__ float redm[4], reds[4];
    float m_ = v;
    for (int o = 32; o > 0; o >>= 1) m_ = fmaxf(m_, __shfl_xor(m_, o));
    if (lane == 0) redm[wid] = m_;
    __syncthreads();
    float bm = fmaxf(fmaxf(redm[0], redm[1]), fmaxf(redm[2], redm[3]));
    float e = __expf(v - bm);
    float s_ = e;
    for (int o = 32; o > 0; o >>= 1) s_ += __shfl_xor(s_, o);
    if (lane == 0) reds[wid] = s_;
    __syncthreads();
    float tot = reds[0] + reds[1] + reds[2] + reds[3];
    attn[hs * S_ + t] = (f16)(e / tot);
}

// attn_out[n][s][h*64+d] = sum_t attn[h][s][t] * vT[n][h][d][t]
__global__ __launch_bounds__(256) void k_pv(const f16* __restrict__ attn,
                                            const f16* __restrict__ vT,
                                            f16* __restrict__ attn_out) {
    int n = blockIdx.x >> 3, h = blockIdx.x & 7;
    int tid = threadIdx.x, lane = tid & 63, wid = tid >> 6;
    __shared__ f16 SH[20480];                    // As 256x64 (16384) + Bs 64x64 (4096)
    f16* As_ = SH;
    f16* Bs_ = SH + 16384;
    f32x4 acc[4][4] = {};
    const f16* Ab = attn + h * S_ * S_;
    const f16* Bb = vT + (n * H_ + h) * 64 * S_;
    for (int tt = 0; tt < 4; ++tt) {
        int t0 = tt << 6;
        __syncthreads();
#pragma unroll
        for (int i = 0; i < 8; ++i) {           // As: 256 rows x 64
            int id = (i << 8) + tid;
            int row = id >> 3, g = (id & 7) ^ (row & 7);
            int lofs = ((i << 8) + (wid << 6)) << 4;
            gl_lds16(Ab + row * S_ + t0 + (g << 3), (char*)As_ + lofs);
        }
#pragma unroll
        for (int i = 0; i < 2; ++i) {           // Bs: 64 rows x 64
            int id = (i << 8) + tid;
            int row = id >> 3, g = (id & 7) ^ (row & 7);
            int lofs = ((i << 8) + (wid << 6)) << 4;
            gl_lds16(Bb + row * S_ + t0 + (g << 3), (char*)Bs_ + lofs);
        }
        __syncthreads();
        frag_mma64(As_, Bs_, lane, wid << 6, 0, acc);
    }
    // epilogue: [128][140] stage halves, coalesced f16x8 stores
#pragma unroll
    for (int p = 0; p < 2; ++p) {
        __syncthreads();
#pragma unroll
        for (int mm = 0; mm < 2; ++mm) {
            int m = 2 * p + mm;
            int rl = ((m & 1) << 4) + ((lane >> 4) << 2);
            int lrow = (wid << 5) + rl;                      // 0..127
#pragma unroll
            for (int j = 0; j < 4; ++j) {
                int d = (j << 4) + (lane & 15);
#pragma unroll
                for (int q = 0; q < 4; ++q)
                    SH[(lrow + q) * 140 + d] = (f16)acc[m][j][q];
            }
        }
        __syncthreads();
#pragma unroll
        for (int i = 0; i < 4; ++i) {
            int u = tid + (i << 8);
            int row = u >> 3, seg = u & 7;
            int s = ((row >> 5) << 6) + (p << 5) + (row & 31);
            *(f16x8*)(attn_out + (n * S_ + s) * C_ + (h << 6) + (seg << 3)) =
                *(const f16x8*)&SH[row * 140 + (seg << 3)];
        }
    }
}

// y = attn_out @ Wout^T + bout; x = msaT + y; LayerNorm(x) -> out[s][n][c]
__global__ __launch_bounds__(512) void k_out_ln(const f16* __restrict__ attn_out,
                                                const f16* __restrict__ Wo,
                                                const float* __restrict__ bout,
                                                const f16* __restrict__ msaT,
                                                const float* __restrict__ gamma,
                                                const float* __restrict__ beta,
                                                float* __restrict__ out) {
    int r0 = blockIdx.x << 6;
    int n = r0 >> 8, s0 = r0 & 255;
    int tid = threadIdx.x, lane = tid & 63, wid = tid >> 6;
    __shared__ f16 SH[36864];                    // As 64x64 (4096) + Bs 512x64 (32768)
    f16* As_ = SH;
    f16* Bs_ = SH + 4096;
    __shared__ float redS[8][64], redQ[8][64], muS[64], rsS[64];
    f32x4 acc[4][4] = {};
    for (int kt = 0; kt < 8; ++kt) {
        int c0 = kt << 6;
        __syncthreads();
        {                                         // As: 64 rows x 64 (1 instr/thread)
            int row = tid >> 3, g = (tid & 7) ^ (row & 7);
            int lofs = (wid << 6) << 4;
            gl_lds16(attn_out + (r0 + row) * C_ + c0 + (g << 3), (char*)As_ + lofs);
        }
#pragma unroll
        for (int i = 0; i < 8; ++i) {             // Bs: 512 rows x 64
            int id = (i << 9) + tid;
            int row = id >> 3, g = (id & 7) ^ (row & 7);
            int lofs = ((i << 9) + (wid << 6)) << 4;
            gl_lds16(Wo + row * C_ + c0 + (g << 3), (char*)Bs_ + lofs);
        }
        __syncthreads();
        frag_mma64(As_, Bs_, lane, 0, wid << 6, acc);
    }
    float psum[4][4] = {}, psq[4][4] = {};
#pragma unroll
    for (int m = 0; m < 4; ++m)
#pragma unroll
        for (int j = 0; j < 4; ++j) {
            int c = (wid << 6) + (j << 4) + (lane & 15);
            float bj = bout[c];
#pragma unroll
            for (int q = 0; q < 4; ++q) {
                int rl = (m << 4) + ((lane >> 4) << 2) + q;
                float x = acc[m][j][q] + bj + (float)msaT[(r0 + rl) * C_ + c];
                acc[m][j][q] = x;
                psum[m][q] += x;
                psq[m][q] += x * x;
            }
        }
#pragma unroll
    for (int m = 0; m < 4; ++m)
#pragma unroll
        for (int q = 0; q < 4; ++q)
            for (int o = 1; o < 16; o <<= 1) {
                psum[m][q] += __shfl_xor(psum[m][q], o);
                psq[m][q]  += __shfl_xor(psq[m][q], o);
            }
    if ((lane & 15) == 0) {
#pragma unroll
        for (int m = 0; m < 4; ++m)
#pragma unroll
            for (int q = 0; q < 4; ++q) {
                int rl = (m << 4) + ((lane >> 4) << 2) + q;
                redS[wid][rl] = psum[m][q];
                redQ[wid][rl] = psq[m][q];
            }
    }
    __syncthreads();
    if (tid < 64) {
        float t1 = 0.f, t2 = 0.f;
#pragma unroll
        for (int w = 0; w < 8; ++w) { t1 += redS[w][tid]; t2 += redQ[w][tid]; }
        float mu = t1 * (1.0f / 512.0f);
        float var = t2 * (1.0f / 512.0f) - mu * mu;
        muS[tid] = mu;
        rsS[tid] = rsqrtf(var + 1e-5f);
    }
    __syncthreads();
#pragma unroll
    for (int m = 0; m < 4; ++m)
#pragma unroll
        for (int j = 0; j < 4; ++j) {
            int c = (wid << 6) + (j << 4) + (lane & 15);
            float g = gamma[c], bb = beta[c];
#pragma unroll
            for (int q = 0; q < 4; ++q) {
                int rl = (m << 4) + ((lane >> 4) << 2) + q;
                int s = s0 + rl;
                float y = (acc[m][j][q] - muS[rl]) * rsS[rl] * g + bb;
                out[(s * N_ + n) * C_ + c] = y;
            }
        }
}

extern "C" void kernel_launch(void* const* d_in, const int* in_sizes, int n_in,
                              void* d_out, int out_size, void* d_ws, size_t ws_size,
                              hipStream_t stream) {
    const float* msa   = (const float*)d_in[0];
    const int*   mask  = (const int*)d_in[1];
    const float* Wqkv  = (const float*)d_in[2];
    const float* bqkv  = (const float*)d_in[3];
    const float* Wout  = (const float*)d_in[4];
    const float* bout  = (const float*)d_in[5];
    const float* gamma = (const float*)d_in[6];
    const float* beta  = (const float*)d_in[7];
    float* out = (float*)d_out;
    char* ws = (char*)d_ws;

    f16*   qk   = (f16*)(ws);                        // 201,326,592 B
    f16*   vT   = (f16*)(ws + 201326592);            // 100,663,296 B
    f16*   msaT = (f16*)(ws + 301989888);            // 100,663,296 B
    f16*   attn = (f16*)(ws + 402653184);            //   1,048,576 B
    f16*   Wq16 = (f16*)(ws + 403701760);            //   1,572,864 B
    f16*   Wo16 = (f16*)(ws + 405274624);            //     524,288 B
    float* logP = out;                               // d_out as scratch (67 MB of 201 MB);
                                                     // k_out_ln overwrites d_out last
    f16*   attn_out = qk;                            // alias: q/k dead after k_logits

    k_cast<<<dim3(24576), dim3(256), 0, stream>>>(msa, Wqkv, Wout, msaT, Wq16, Wo16);
    k_qkv<<<dim3(9216), dim3(512), 0, stream>>>(msaT, Wq16, bqkv, qk, vT);
    k_logits<<<dim3(1024), dim3(512), 0, stream>>>(qk, logP);
    k_softmax<<<dim3(2048), dim3(256), 0, stream>>>(logP, mask, attn);
    k_pv<<<dim3(3072), dim3(256), 0, stream>>>(attn, vT, attn_out);
    k_out_ln<<<dim3(1536), dim3(512), 0, stream>>>(attn_out, Wo16, bout, msaT, gamma, beta, out);
}